// Round 1
// baseline (349.212 us; speedup 1.0000x reference)
//
#include <hip/hip_runtime.h>

typedef __attribute__((ext_vector_type(8))) short bf16x8;
typedef __attribute__((ext_vector_type(4))) float f32x4;

#define MFMA16(a,b,c) __builtin_amdgcn_mfma_f32_16x16x32_bf16((a),(b),(c),0,0,0)

#if __has_builtin(__builtin_amdgcn_exp2f)
#define EXP2(x) __builtin_amdgcn_exp2f(x)
#else
#define EXP2(x) exp2f(x)
#endif

#define NB   2
#define NSEQ 2048
#define NH   8
#define ND   64
#define FIN  512
#define MD   512                 // H*D
#define NTOK (NB * NSEQ)         // 4096
// (1/sqrt(64)) * log2(e)
#define SCALE_LOG2E 0.18033688011112042f

// ---- sizes in elements ----
#define HT_ELEMS   (NB * NH * NSEQ * ND)   // 2097152 bf16
#define L_ELEMS    (NB * NH * NSEQ)        // 32768 fp32 (per half)
#define O_ELEMS    (NTOK * MD)             // 2097152 fp32 (per half)

static __device__ __forceinline__ unsigned short f2b(float f) {
  union { float f; unsigned u; } c; c.f = f;
  unsigned u = c.u;
  u += 0x7fffu + ((u >> 16) & 1u);   // RNE; inputs are finite
  return (unsigned short)(u >> 16);
}

// ============================================================================
// Kernel A: h = bf16(x @ W + b), written in two layouts:
//   h_t[b][h][n][d]  (row-major, for Q/K fragments)
//   h_d[b][h][d][n]  (d-major,   for V fragments)
// Tile 64x64, BK=32, grid (4096/64, 512/64) = (64, 8), 256 threads.
// ============================================================================
__global__ __launch_bounds__(256, 2)
void proj_kernel(const float* __restrict__ X, const float* __restrict__ W,
                 const float* __restrict__ bias,
                 unsigned short* __restrict__ h_t, unsigned short* __restrict__ h_d) {
  __shared__ __align__(16) unsigned short sA[64][40];  // [m][k], pitch 40 (80B, 16B-aligned)
  __shared__ __align__(16) unsigned short sB[64][40];  // [n][k]
  const int t = threadIdx.x;
  const int w = t >> 6, L = t & 63, l15 = L & 15, qd = L >> 4;
  const int bm = blockIdx.x, bn = blockIdx.y;

  f32x4 acc[4];
  for (int q = 0; q < 4; ++q) acc[q] = (f32x4){0.f, 0.f, 0.f, 0.f};

  for (int ks = 0; ks < FIN; ks += 32) {
    __syncthreads();
    {
      int col = t & 31, row = t >> 5;           // A: 64x32
      for (int i = 0; i < 8; ++i) {
        float v = X[(size_t)(bm * 64 + row + 8 * i) * FIN + ks + col];
        sA[row + 8 * i][col] = f2b(v);
      }
      int n = t & 63, k = t >> 6;               // B: 32x64 -> transposed store
      for (int i = 0; i < 8; ++i) {
        float v = W[(size_t)(ks + k + 4 * i) * MD + bn * 64 + n];
        sB[n][k + 4 * i] = f2b(v);
      }
    }
    __syncthreads();
    bf16x8 af = *(const bf16x8*)&sA[16 * w + l15][qd * 8];
    for (int q = 0; q < 4; ++q) {
      bf16x8 bf = *(const bf16x8*)&sB[16 * q + l15][qd * 8];
      acc[q] = MFMA16(af, bf, acc[q]);
    }
  }

  for (int q = 0; q < 4; ++q) {
    int feat = bn * 64 + 16 * q + l15;
    int hh = feat >> 6, dd = feat & 63;
    float bv = bias[feat];
    int token0 = bm * 64 + 16 * w + qd * 4;     // 4-aligned, never crosses b
    unsigned short pk[4];
    for (int r = 0; r < 4; ++r) {
      float v = acc[q][r] + bv;
      unsigned short bb = f2b(v);
      int token = token0 + r;
      int b = token >> 11, n = token & 2047;
      h_t[((size_t)(b * NH + hh) * NSEQ + n) * ND + dd] = bb;
      pk[r] = bb;
    }
    int b = token0 >> 11, n0 = token0 & 2047;
    *(ushort4*)&h_d[((size_t)(b * NH + hh) * ND + dd) * NSEQ + n0] =
        make_ushort4(pk[0], pk[1], pk[2], pk[3]);
  }
}

// ============================================================================
// Kernel B: l_part[half][b][h][n] = sum over m-half of mask*exp(s/8)
// grid (256, 2): x = b*128+rblk (16 query rows), y = m-half. 256 threads.
// ============================================================================
__global__ __launch_bounds__(256, 2)
void stats_kernel(const unsigned short* __restrict__ h_t, const int* __restrict__ adj,
                  float* __restrict__ l_part) {
  const int t = threadIdx.x;
  const int w = t >> 6, L = t & 63, l15 = L & 15, qd = L >> 4;
  const int b = blockIdx.x >> 7, rblk = blockIdx.x & 127, half = blockIdx.y;
  const int r0 = rblk * 16;
  __shared__ float redbuf[4][NH][16];

  bf16x8 qf[NH][2];
  for (int h = 0; h < NH; ++h)
    for (int kk = 0; kk < 2; ++kk)
      qf[h][kk] = *(const bf16x8*)&h_t[((size_t)(b * NH + h) * NSEQ + r0 + l15) * ND + kk * 32 + qd * 8];

  float lacc[NH][4];
  for (int h = 0; h < NH; ++h)
    for (int r = 0; r < 4; ++r) lacc[h][r] = 0.f;

  for (int it = 0; it < 16; ++it) {
    int m0 = half * 1024 + it * 64;
    int colg = m0 + 16 * w + l15;
    int mok[4];
    for (int r = 0; r < 4; ++r)
      mok[r] = adj[((size_t)b * NSEQ + r0 + qd * 4 + r) * NSEQ + colg];
    for (int h = 0; h < NH; ++h) {
      const unsigned short* kb = &h_t[((size_t)(b * NH + h) * NSEQ + colg) * ND + qd * 8];
      bf16x8 k0 = *(const bf16x8*)kb;
      bf16x8 k1 = *(const bf16x8*)(kb + 32);
      f32x4 z = (f32x4){0.f, 0.f, 0.f, 0.f};
      f32x4 acc = MFMA16(qf[h][0], k0, z);
      acc = MFMA16(qf[h][1], k1, acc);
      for (int r = 0; r < 4; ++r) {
        float e = EXP2(acc[r] * SCALE_LOG2E);
        lacc[h][r] += mok[r] ? e : 0.f;
      }
    }
  }
  for (int h = 0; h < NH; ++h)
    for (int r = 0; r < 4; ++r) {
      float v = lacc[h][r];
      v += __shfl_xor(v, 1); v += __shfl_xor(v, 2);
      v += __shfl_xor(v, 4); v += __shfl_xor(v, 8);
      if (l15 == 0) redbuf[w][h][qd * 4 + r] = v;
    }
  __syncthreads();
  if (t < 128) {
    int h = t >> 4, row = t & 15;
    float s = redbuf[0][h][row] + redbuf[1][h][row] + redbuf[2][h][row] + redbuf[3][h][row];
    l_part[(size_t)half * L_ELEMS + (size_t)(b * NH + h) * NSEQ + r0 + row] = s;
  }
}

// ============================================================================
// Kernel C: p = mask*exp(s/8)/l; attn_mean written once (head-inner loop),
// O = P@V accumulated per head; grid (256, 2), 256 threads.
// ============================================================================
__global__ __launch_bounds__(256, 2)
void attn_kernel(const unsigned short* __restrict__ h_t, const unsigned short* __restrict__ h_d,
                 const int* __restrict__ adj, const float* __restrict__ l_part,
                 float* __restrict__ o_part, float* __restrict__ mean_out) {
  const int t = threadIdx.x;
  const int w = t >> 6, L = t & 63, l15 = L & 15, qd = L >> 4;
  const int b = blockIdx.x >> 7, rblk = blockIdx.x & 127, half = blockIdx.y;
  const int r0 = rblk * 16;
  __shared__ float s_inv[NH][16];
  __shared__ __align__(16) unsigned short s_p[2][16][72];  // pitch 72 (144B = 9*16)

  if (t < 128) {
    int h = t >> 4, row = t & 15;
    size_t idx = (size_t)(b * NH + h) * NSEQ + r0 + row;
    s_inv[h][row] = 1.0f / (l_part[idx] + l_part[(size_t)L_ELEMS + idx]);
  }

  bf16x8 qf[NH][2];
  for (int h = 0; h < NH; ++h)
    for (int kk = 0; kk < 2; ++kk)
      qf[h][kk] = *(const bf16x8*)&h_t[((size_t)(b * NH + h) * NSEQ + r0 + l15) * ND + kk * 32 + qd * 8];

  f32x4 oacc[NH];
  for (int h = 0; h < NH; ++h) oacc[h] = (f32x4){0.f, 0.f, 0.f, 0.f};

  __syncthreads();

  for (int it = 0; it < 16; ++it) {
    int m0 = half * 1024 + it * 64;
    int colg = m0 + 16 * w + l15;
    int mok[4];
    for (int r = 0; r < 4; ++r)
      mok[r] = adj[((size_t)b * NSEQ + r0 + qd * 4 + r) * NSEQ + colg];
    float macc[4] = {0.f, 0.f, 0.f, 0.f};

    for (int h = 0; h < NH; ++h) {
      const unsigned short* kb = &h_t[((size_t)(b * NH + h) * NSEQ + colg) * ND + qd * 8];
      bf16x8 k0 = *(const bf16x8*)kb;
      bf16x8 k1 = *(const bf16x8*)(kb + 32);
      f32x4 z = (f32x4){0.f, 0.f, 0.f, 0.f};
      f32x4 acc = MFMA16(qf[h][0], k0, z);
      acc = MFMA16(qf[h][1], k1, acc);

      int buf = h & 1;
      for (int r = 0; r < 4; ++r) {
        int row4 = qd * 4 + r;
        float p = mok[r] ? EXP2(acc[r] * SCALE_LOG2E) * s_inv[h][row4] : 0.f;
        macc[r] += p;
        s_p[buf][row4][16 * w + l15] = f2b(p);
      }
      __syncthreads();
      // P in A-frag layout: A[m=l15][k=qd*8+j (+32)]
      bf16x8 a0 = *(const bf16x8*)&s_p[buf][l15][qd * 8];
      bf16x8 a1 = *(const bf16x8*)&s_p[buf][l15][32 + qd * 8];
      const unsigned short* vb = &h_d[((size_t)(b * NH + h) * ND + 16 * w + l15) * NSEQ + m0 + qd * 8];
      bf16x8 v0 = *(const bf16x8*)vb;
      bf16x8 v1 = *(const bf16x8*)(vb + 32);
      oacc[h] = MFMA16(a0, v0, oacc[h]);
      oacc[h] = MFMA16(a1, v1, oacc[h]);
    }
    for (int r = 0; r < 4; ++r)
      mean_out[((size_t)b * NSEQ + r0 + qd * 4 + r) * NSEQ + colg] = macc[r] * 0.125f;
  }

  for (int h = 0; h < NH; ++h)
    for (int r = 0; r < 4; ++r) {
      size_t token = (size_t)b * NSEQ + r0 + qd * 4 + r;
      o_part[(size_t)half * O_ELEMS + token * MD + h * ND + 16 * w + l15] = oacc[h][r];
    }
}

// ============================================================================
// Kernel D: out = LN(o_part[0] + o_part[1]) * gamma + beta. One row per block.
// ============================================================================
__global__ __launch_bounds__(256)
void ln_kernel(const float* __restrict__ o_part, const float* __restrict__ gamma,
               const float* __restrict__ beta, float* __restrict__ out) {
  const int row = blockIdx.x, t = threadIdx.x;
  const float* p0 = o_part + (size_t)row * MD;
  const float* p1 = o_part + (size_t)O_ELEMS + (size_t)row * MD;
  float v0 = p0[t] + p1[t];
  float v1 = p0[t + 256] + p1[t + 256];
  float s = v0 + v1, sq = v0 * v0 + v1 * v1;
  for (int m = 1; m < 64; m <<= 1) { s += __shfl_xor(s, m); sq += __shfl_xor(sq, m); }
  __shared__ float rs[4], rq[4];
  if ((t & 63) == 0) { rs[t >> 6] = s; rq[t >> 6] = sq; }
  __syncthreads();
  s = rs[0] + rs[1] + rs[2] + rs[3];
  sq = rq[0] + rq[1] + rq[2] + rq[3];
  float mu = s * (1.f / MD);
  float var = sq * (1.f / MD) - mu * mu;
  float rstd = rsqrtf(var + 1e-5f);
  out[(size_t)row * MD + t]       = (v0 - mu) * rstd * gamma[t] + beta[t];
  out[(size_t)row * MD + t + 256] = (v1 - mu) * rstd * gamma[t + 256] + beta[t + 256];
}

// ============================================================================
extern "C" void kernel_launch(void* const* d_in, const int* in_sizes, int n_in,
                              void* d_out, int out_size, void* d_ws, size_t ws_size,
                              hipStream_t stream) {
  const float* x     = (const float*)d_in[0];
  const int*   adj   = (const int*)d_in[1];
  const float* W     = (const float*)d_in[2];
  const float* Wb    = (const float*)d_in[3];
  const float* gamma = (const float*)d_in[4];
  const float* beta  = (const float*)d_in[5];
  float* out = (float*)d_out;

  unsigned short* h_t = (unsigned short*)d_ws;           // 2M bf16 = 4 MB
  unsigned short* h_d = h_t + HT_ELEMS;                  // 2M bf16 = 4 MB
  float* l_part = (float*)(h_d + HT_ELEMS);              // 2*32768 fp32 = 256 KB
  float* o_part = l_part + 2 * L_ELEMS;                  // 2*2M fp32 = 16 MB

  proj_kernel<<<dim3(64, 8), 256, 0, stream>>>(x, W, Wb, h_t, h_d);
  stats_kernel<<<dim3(256, 2), 256, 0, stream>>>(h_t, adj, l_part);
  attn_kernel<<<dim3(256, 2), 256, 0, stream>>>(h_t, h_d, adj, l_part, o_part,
                                                out + (size_t)NTOK * MD);
  ln_kernel<<<NTOK, 256, 0, stream>>>(o_part, gamma, beta, out);
}

// Round 3
// 263.645 us; speedup vs baseline: 1.3246x; 1.3246x over previous
//
#include <hip/hip_runtime.h>

typedef __attribute__((ext_vector_type(8))) short bf16x8;
typedef __attribute__((ext_vector_type(4))) short bf16x4;
typedef __attribute__((ext_vector_type(4))) float f32x4;
typedef __attribute__((ext_vector_type(4))) int i32x4;

static __device__ __forceinline__ f32x4 MFMA_QK(bf16x8 a, bf16x8 b, f32x4 c) {
  return __builtin_amdgcn_mfma_f32_16x16x32_bf16(a, b, c, 0, 0, 0);
}

#if __has_builtin(__builtin_amdgcn_mfma_f32_16x16x16bf16_1k)
static __device__ __forceinline__ f32x4 MFMA_PV(bf16x4 a, bf16x4 b, f32x4 c) {
  return __builtin_amdgcn_mfma_f32_16x16x16bf16_1k(a, b, c, 0, 0, 0);
}
#define PV_EPILOGUE_GUARD()
#else
static __device__ __forceinline__ f32x4 MFMA_PV(bf16x4 a, bf16x4 b, f32x4 c) {
  asm("v_mfma_f32_16x16x16_bf16 %0, %1, %2, %0" : "+v"(c) : "v"(a), "v"(b));
  return c;
}
#define PV_EPILOGUE_GUARD() asm volatile("s_nop 7\ns_nop 7" :::)
#endif

#if __has_builtin(__builtin_amdgcn_exp2f)
#define EXP2(x) __builtin_amdgcn_exp2f(x)
#else
#define EXP2(x) exp2f(x)
#endif

#define NB   2
#define NSEQ 2048
#define NH   8
#define ND   64
#define FIN  512
#define MD   512
#define NTOK (NB * NSEQ)
#define SCALE_LOG2E 0.18033688011112042f   // (1/sqrt(64)) * log2(e)

#define XB_ELEMS   (NTOK * FIN)            // 2097152 bf16
#define WT_ELEMS   (MD * FIN)              // 262144 bf16
#define HT_ELEMS   (NB * NH * NSEQ * ND)   // 2097152 bf16
#define L_ELEMS    (NB * NH * NSEQ)        // 32768 fp32 per half
#define O_ELEMS    (NTOK * MD)             // 2097152 fp32 per half

static __device__ __forceinline__ unsigned short f2b(float f) {
  union { float f; unsigned u; } c; c.f = f;
  unsigned u = c.u;
  u += 0x7fffu + ((u >> 16) & 1u);   // RNE; inputs finite
  return (unsigned short)(u >> 16);
}

static __device__ __forceinline__ unsigned pack2(float a, float b) {
#if __has_builtin(__builtin_amdgcn_cvt_pk_bf16_f32)
  auto v = __builtin_amdgcn_cvt_pk_bf16_f32(a, b);
  unsigned r; __builtin_memcpy(&r, &v, 4); return r;
#else
  return (unsigned)f2b(a) | ((unsigned)f2b(b) << 16);
#endif
}

// ============================================================================
// Convert x -> bf16 (xb, row-major) and W -> bf16 transposed (wt[n][k]).
// ============================================================================
__global__ __launch_bounds__(256)
void cvt_kernel(const float* __restrict__ x, const float* __restrict__ W,
                unsigned short* __restrict__ xb, unsigned short* __restrict__ wt) {
  const int t = threadIdx.x;
  if (blockIdx.x < 2048) {
    size_t i = ((size_t)blockIdx.x * 256 + t) * 4;
    f32x4 v = *(const f32x4*)(x + i);
    ushort4 o = make_ushort4(f2b(v[0]), f2b(v[1]), f2b(v[2]), f2b(v[3]));
    *(ushort4*)(xb + i) = o;
  } else {
    int j = ((int)(blockIdx.x - 2048) * 256 + t) * 4;
    int k = j >> 9, n = j & 511;
    f32x4 v = *(const f32x4*)(W + (size_t)k * MD + n);
    wt[(size_t)(n + 0) * FIN + k] = f2b(v[0]);
    wt[(size_t)(n + 1) * FIN + k] = f2b(v[1]);
    wt[(size_t)(n + 2) * FIN + k] = f2b(v[2]);
    wt[(size_t)(n + 3) * FIN + k] = f2b(v[3]);
  }
}

// ============================================================================
// Projection GEMM (bf16 in, bf16 out in 2 layouts). 64x64 tile, BK=64.
// ============================================================================
__global__ __launch_bounds__(256, 2)
void proj_kernel(const unsigned short* __restrict__ xb, const unsigned short* __restrict__ wt,
                 const float* __restrict__ bias,
                 unsigned short* __restrict__ h_t, unsigned short* __restrict__ h_d) {
  __shared__ __align__(16) unsigned short sA[64][72];
  __shared__ __align__(16) unsigned short sB[64][72];
  const int t = threadIdx.x;
  const int w = t >> 6, L = t & 63, l15 = L & 15, qd = L >> 4;
  const int bm = blockIdx.x, bn = blockIdx.y;
  const int r = t >> 3, c8 = (t & 7) * 8;
  const f32x4 ZERO4 = {0.f, 0.f, 0.f, 0.f};

  f32x4 acc[4];
  #pragma unroll
  for (int q = 0; q < 4; ++q) acc[q] = ZERO4;

  for (int ks = 0; ks < FIN; ks += 64) {
    __syncthreads();
    *(bf16x8*)&sA[r][c8]      = *(const bf16x8*)&xb[(size_t)(bm*64 + r)      * FIN + ks + c8];
    *(bf16x8*)&sA[r + 32][c8] = *(const bf16x8*)&xb[(size_t)(bm*64 + r + 32) * FIN + ks + c8];
    *(bf16x8*)&sB[r][c8]      = *(const bf16x8*)&wt[(size_t)(bn*64 + r)      * FIN + ks + c8];
    *(bf16x8*)&sB[r + 32][c8] = *(const bf16x8*)&wt[(size_t)(bn*64 + r + 32) * FIN + ks + c8];
    __syncthreads();
    #pragma unroll
    for (int kk = 0; kk < 2; ++kk) {
      bf16x8 af = *(const bf16x8*)&sA[16*w + l15][kk*32 + qd*8];
      #pragma unroll
      for (int q = 0; q < 4; ++q) {
        bf16x8 bf = *(const bf16x8*)&sB[16*q + l15][kk*32 + qd*8];
        acc[q] = MFMA_QK(af, bf, acc[q]);
      }
    }
  }

  #pragma unroll
  for (int q = 0; q < 4; ++q) {
    int feat = bn * 64 + 16 * q + l15;
    int hh = feat >> 6, dd = feat & 63;
    float bv = bias[feat];
    int token0 = bm * 64 + 16 * w + qd * 4;   // 4-aligned, never crosses b
    unsigned short pk[4];
    #pragma unroll
    for (int rr = 0; rr < 4; ++rr) {
      float v = acc[q][rr] + bv;
      unsigned short bb = f2b(v);
      int token = token0 + rr;
      int b = token >> 11, n = token & 2047;
      h_t[((size_t)(b * NH + hh) * NSEQ + n) * ND + dd] = bb;
      pk[rr] = bb;
    }
    int b = token0 >> 11, n0 = token0 & 2047;
    *(ushort4*)&h_d[((size_t)(b * NH + hh) * ND + dd) * NSEQ + n0] =
        make_ushort4(pk[0], pk[1], pk[2], pk[3]);
  }
}

// ============================================================================
// Stats: l_part[half][b][h][n] = sum over m-half of mask*exp(s/8).
// 8 waves = 8 heads, 32 query rows/block, S^T formulation (no LDS transpose).
// ============================================================================
__global__ __launch_bounds__(512, 2)
void stats_kernel(const unsigned short* __restrict__ h_t, const int* __restrict__ adj,
                  float* __restrict__ l_part) {
  const int t = threadIdx.x;
  const int h = t >> 6, L = t & 63, l15 = L & 15, qd = L >> 4;
  const int u = blockIdx.x & 7;                  // XCD id spread
  const int b = u >> 2;
  const int rblk = ((int)blockIdx.x >> 3) * 4 + (u & 3);
  const int half = blockIdx.y;
  const int n0 = rblk * 32;
  __shared__ __align__(16) float s_mask[32][68];
  const f32x4 ZERO4 = {0.f, 0.f, 0.f, 0.f};

  const unsigned short* hb = h_t + (size_t)(b * NH + h) * NSEQ * ND;
  bf16x8 qf[2][2];
  #pragma unroll
  for (int g = 0; g < 2; ++g)
    #pragma unroll
    for (int kk = 0; kk < 2; ++kk)
      qf[g][kk] = *(const bf16x8*)&hb[(size_t)(n0 + g*16 + l15) * ND + kk*32 + qd*8];

  float lacc[2] = {0.f, 0.f};
  const int cr = t >> 4, cc4 = (t & 15) * 4;

  for (int it = 0; it < 16; ++it) {
    const int c0 = half * 1024 + it * 64;
    __syncthreads();
    {
      i32x4 av = *(const i32x4*)&adj[((size_t)b * NSEQ + n0 + cr) * NSEQ + c0 + cc4];
      f32x4 mv;
      mv[0] = av[0] ? 1.f : 0.f; mv[1] = av[1] ? 1.f : 0.f;
      mv[2] = av[2] ? 1.f : 0.f; mv[3] = av[3] ? 1.f : 0.f;
      *(f32x4*)&s_mask[cr][cc4] = mv;
    }
    __syncthreads();
    #pragma unroll
    for (int cc = 0; cc < 4; ++cc) {
      const unsigned short* kp = &hb[(size_t)(c0 + cc*16 + l15) * ND + qd*8];
      bf16x8 kf0 = *(const bf16x8*)kp;
      bf16x8 kf1 = *(const bf16x8*)(kp + 32);
      #pragma unroll
      for (int g = 0; g < 2; ++g) {
        f32x4 s = MFMA_QK(kf0, qf[g][0], ZERO4);
        s = MFMA_QK(kf1, qf[g][1], s);
        f32x4 mv = *(const f32x4*)&s_mask[g*16 + l15][cc*16 + qd*4];
        #pragma unroll
        for (int rr = 0; rr < 4; ++rr)
          lacc[g] += mv[rr] * EXP2(s[rr] * SCALE_LOG2E);
      }
    }
  }
  #pragma unroll
  for (int g = 0; g < 2; ++g) {
    float v = lacc[g];
    v += __shfl_xor(v, 16);
    v += __shfl_xor(v, 32);
    if (L < 16)
      l_part[(size_t)half * L_ELEMS + (size_t)(b * NH + h) * NSEQ + n0 + g*16 + L] = v;
  }
}

// ============================================================================
// Attention: P = mask*exp(s/8)/l via S^T trick; PV as O^T = V^T P^T entirely
// in registers; mean reduced across waves (heads) through LDS once per iter.
// ============================================================================
__global__ __launch_bounds__(512, 2)
void attn_kernel(const unsigned short* __restrict__ h_t, const unsigned short* __restrict__ h_d,
                 const int* __restrict__ adj, const float* __restrict__ l_part,
                 float* __restrict__ o_part, float* __restrict__ mean_out) {
  const int t = threadIdx.x;
  const int h = t >> 6, L = t & 63, l15 = L & 15, qd = L >> 4;
  const int u = blockIdx.x & 7;
  const int b = u >> 2;
  const int rblk = ((int)blockIdx.x >> 3) * 4 + (u & 3);
  const int half = blockIdx.y;
  const int n0 = rblk * 32;
  __shared__ __align__(16) float s_mask[32][68];                 // 8.7 KB
  __shared__ __align__(16) unsigned short s_part[8][32][72];     // 36.9 KB, bf16 P partials
  const f32x4 ZERO4 = {0.f, 0.f, 0.f, 0.f};

  const unsigned short* hb = h_t + (size_t)(b * NH + h) * NSEQ * ND;
  const unsigned short* vb = h_d + (size_t)(b * NH + h) * ND * NSEQ;

  bf16x8 qf[2][2];
  #pragma unroll
  for (int g = 0; g < 2; ++g)
    #pragma unroll
    for (int kk = 0; kk < 2; ++kk)
      qf[g][kk] = *(const bf16x8*)&hb[(size_t)(n0 + g*16 + l15) * ND + kk*32 + qd*8];

  float linv[2];
  #pragma unroll
  for (int g = 0; g < 2; ++g) {
    size_t idx = (size_t)(b * NH + h) * NSEQ + n0 + g*16 + l15;
    float ls = l_part[idx] + l_part[(size_t)L_ELEMS + idx];
    linv[g] = -__log2f(ls);
  }

  f32x4 oacc[2][4];
  #pragma unroll
  for (int g = 0; g < 2; ++g)
    #pragma unroll
    for (int dc = 0; dc < 4; ++dc) oacc[g][dc] = ZERO4;

  const int cr = t >> 4, cc4 = (t & 15) * 4;

  for (int it = 0; it < 16; ++it) {
    const int c0 = half * 1024 + it * 64;
    __syncthreads();   // A: protect s_mask + s_part reuse
    {
      i32x4 av = *(const i32x4*)&adj[((size_t)b * NSEQ + n0 + cr) * NSEQ + c0 + cc4];
      f32x4 mv;
      mv[0] = av[0] ? 1.f : 0.f; mv[1] = av[1] ? 1.f : 0.f;
      mv[2] = av[2] ? 1.f : 0.f; mv[3] = av[3] ? 1.f : 0.f;
      *(f32x4*)&s_mask[cr][cc4] = mv;
    }
    __syncthreads();   // B: mask ready
    #pragma unroll
    for (int cc = 0; cc < 4; ++cc) {
      const int ccol = c0 + cc * 16;
      const unsigned short* kp = &hb[(size_t)(ccol + l15) * ND + qd*8];
      bf16x8 kf0 = *(const bf16x8*)kp;
      bf16x8 kf1 = *(const bf16x8*)(kp + 32);
      bf16x4 va[4];
      #pragma unroll
      for (int dc = 0; dc < 4; ++dc)
        va[dc] = *(const bf16x4*)&vb[(size_t)(dc*16 + l15) * NSEQ + ccol + qd*4];
      #pragma unroll
      for (int g = 0; g < 2; ++g) {
        f32x4 s = MFMA_QK(kf0, qf[g][0], ZERO4);
        s = MFMA_QK(kf1, qf[g][1], s);
        f32x4 mv = *(const f32x4*)&s_mask[g*16 + l15][cc*16 + qd*4];
        f32x4 p;
        #pragma unroll
        for (int rr = 0; rr < 4; ++rr)
          p[rr] = mv[rr] * EXP2(__builtin_fmaf(s[rr], SCALE_LOG2E, linv[g]));
        union { unsigned u2[2]; bf16x4 v4; uint2 d; } pk;
        pk.u2[0] = pack2(p[0], p[1]);
        pk.u2[1] = pack2(p[2], p[3]);
        *(uint2*)&s_part[h][g*16 + l15][cc*16 + qd*4] = pk.d;
        #pragma unroll
        for (int dc = 0; dc < 4; ++dc)
          oacc[g][dc] = MFMA_PV(va[dc], pk.v4, oacc[g][dc]);
      }
    }
    __syncthreads();   // C: partials ready
    {
      f32x4 macc = ZERO4;
      #pragma unroll
      for (int hh = 0; hh < 8; ++hh) {
        uint2 pv = *(const uint2*)&s_part[hh][cr][cc4];
        union { unsigned u; float f; } a0, a1, a2, a3;
        a0.u = pv.x << 16; a1.u = pv.x & 0xffff0000u;
        a2.u = pv.y << 16; a3.u = pv.y & 0xffff0000u;
        macc[0] += a0.f; macc[1] += a1.f; macc[2] += a2.f; macc[3] += a3.f;
      }
      macc *= 0.125f;
      *(f32x4*)&mean_out[((size_t)b * NSEQ + n0 + cr) * NSEQ + c0 + cc4] = macc;
    }
  }

  PV_EPILOGUE_GUARD();
  #pragma unroll
  for (int g = 0; g < 2; ++g)
    #pragma unroll
    for (int dc = 0; dc < 4; ++dc) {
      size_t token = (size_t)b * NSEQ + n0 + g*16 + l15;
      *(f32x4*)&o_part[(size_t)half * O_ELEMS + token * MD + h*64 + dc*16 + qd*4] =
          oacc[g][dc];
    }
}

// ============================================================================
// LayerNorm over model dim; sums the two column-half O partials.
// ============================================================================
__global__ __launch_bounds__(256)
void ln_kernel(const float* __restrict__ o_part, const float* __restrict__ gamma,
               const float* __restrict__ beta, float* __restrict__ out) {
  const int row = blockIdx.x, t = threadIdx.x;
  const float* p0 = o_part + (size_t)row * MD;
  const float* p1 = o_part + (size_t)O_ELEMS + (size_t)row * MD;
  float v0 = p0[t] + p1[t];
  float v1 = p0[t + 256] + p1[t + 256];
  float s = v0 + v1, sq = v0 * v0 + v1 * v1;
  for (int m = 1; m < 64; m <<= 1) { s += __shfl_xor(s, m); sq += __shfl_xor(sq, m); }
  __shared__ float rs[4], rq[4];
  if ((t & 63) == 0) { rs[t >> 6] = s; rq[t >> 6] = sq; }
  __syncthreads();
  s = rs[0] + rs[1] + rs[2] + rs[3];
  sq = rq[0] + rq[1] + rq[2] + rq[3];
  float mu = s * (1.f / MD);
  float var = sq * (1.f / MD) - mu * mu;
  float rstd = rsqrtf(var + 1e-5f);
  out[(size_t)row * MD + t]       = (v0 - mu) * rstd * gamma[t] + beta[t];
  out[(size_t)row * MD + t + 256] = (v1 - mu) * rstd * gamma[t + 256] + beta[t + 256];
}

// ============================================================================
extern "C" void kernel_launch(void* const* d_in, const int* in_sizes, int n_in,
                              void* d_out, int out_size, void* d_ws, size_t ws_size,
                              hipStream_t stream) {
  const float* x     = (const float*)d_in[0];
  const int*   adj   = (const int*)d_in[1];
  const float* W     = (const float*)d_in[2];
  const float* Wb    = (const float*)d_in[3];
  const float* gamma = (const float*)d_in[4];
  const float* beta  = (const float*)d_in[5];
  float* out = (float*)d_out;

  unsigned short* xb  = (unsigned short*)d_ws;     // 4 MB
  unsigned short* wt  = xb + XB_ELEMS;             // 0.5 MB
  unsigned short* h_t = wt + WT_ELEMS;             // 4 MB
  unsigned short* h_d = h_t + HT_ELEMS;            // 4 MB
  float* l_part = (float*)(h_d + HT_ELEMS);        // 256 KB
  float* o_part = l_part + 2 * L_ELEMS;            // 16 MB

  cvt_kernel<<<2304, 256, 0, stream>>>(x, W, xb, wt);
  proj_kernel<<<dim3(64, 8), 256, 0, stream>>>(xb, wt, Wb, h_t, h_d);
  stats_kernel<<<dim3(128, 2), 512, 0, stream>>>(h_t, adj, l_part);
  attn_kernel<<<dim3(128, 2), 512, 0, stream>>>(h_t, h_d, adj, l_part, o_part,
                                                out + (size_t)NTOK * MD);
  ln_kernel<<<NTOK, 256, 0, stream>>>(o_part, gamma, beta, out);
}